// Round 5
// baseline (7389.545 us; speedup 1.0000x reference)
//
#include <hip/hip_runtime.h>

typedef __bf16 bf16;
typedef bf16 bf16x8 __attribute__((ext_vector_type(8)));
typedef float f32x4 __attribute__((ext_vector_type(4)));

#define NB 256     // batch
#define TS 64      // timesteps
#define DD 1024    // input dim
#define HH 1024    // hidden
#define KTOT 3072  // D + 2H (fused GEMM K)
#define NOUT 4096  // 4H
#define KTILES 96  // KTOT/32
#define KSPLIT 4   // K-split (4 x 768)
#define KT_PER 24  // ktiles per split
#define GITERS 12  // BK=64 iters per split
#define PSTRIDE (NB * NOUT)
#define NWG 256    // persistent grid = one wg per CU

// Weights fragment-tiled (16n x 32k tiles of 512 bf16; element (l,j):
// n=base+(l&15), k=kbase+(l>>4)*8+j) -> global_load_lds staging is linear.
// Activations Aop row-major bf16 (256 x 3072); GEMM gathers via per-lane
// global source addresses (m173), LDS dest stays linear.

static __device__ __forceinline__ void gload_lds16(const void* g, void* l) {
  __builtin_amdgcn_global_load_lds(
      (const __attribute__((address_space(1))) void*)g,
      (__attribute__((address_space(3))) void*)l, 16, 0, 0);
}

// Grid barrier: device-scope atomics + monotonic generation (no reset race:
// cnt reset happens-before gen release; waiters poll gen only). All wgs call
// gsync the same number of times with the same epoch e.
static __device__ __forceinline__ void gsync(unsigned* cnt, unsigned* gen, unsigned e) {
  __syncthreads();
  if (threadIdx.x == 0) {
    __threadfence();  // release: flush our preact/Aop/out writes device-wide
    const unsigned arrived =
        __hip_atomic_fetch_add(cnt, 1u, __ATOMIC_ACQ_REL, __HIP_MEMORY_SCOPE_AGENT);
    if (arrived == NWG - 1) {
      __hip_atomic_store(cnt, 0u, __ATOMIC_RELAXED, __HIP_MEMORY_SCOPE_AGENT);
      __hip_atomic_store(gen, e, __ATOMIC_RELEASE, __HIP_MEMORY_SCOPE_AGENT);
    } else {
      while (__hip_atomic_load(gen, __ATOMIC_ACQUIRE, __HIP_MEMORY_SCOPE_AGENT) < e)
        __builtin_amdgcn_s_sleep(4);
    }
    __threadfence();  // acquire: invalidate stale L1/L2 lines before reads
  }
  __syncthreads();
}

// scores -> softmax -> attn -> pack (R3-proven). 1024 threads, h_sh written.
// Wave w owns position p=w; lane sums h over units lane+64i; 5 ds_swizzle
// XOR butterflies reduce 32-lane halves; halves summed via LDS.
static __device__ __forceinline__ void attn_tail(
    int n, int u, const float* __restrict__ A, bf16* __restrict__ Aop,
    const float* __restrict__ h_sh, float* __restrict__ scA,
    float* __restrict__ scB) {
  const int lane = u & 63, w = u >> 6;
  const float* ap = A + (size_t)n * (HH * 16) + w;
  float s = 0.f;
#pragma unroll
  for (int i = 0; i < 16; ++i) {
    const int idx = lane + 64 * i;
    s = fmaf(h_sh[idx], ap[(size_t)idx * 16], s);
  }
  s += __int_as_float(__builtin_amdgcn_ds_swizzle(__float_as_int(s), 0x041F));
  s += __int_as_float(__builtin_amdgcn_ds_swizzle(__float_as_int(s), 0x081F));
  s += __int_as_float(__builtin_amdgcn_ds_swizzle(__float_as_int(s), 0x101F));
  s += __int_as_float(__builtin_amdgcn_ds_swizzle(__float_as_int(s), 0x201F));
  s += __int_as_float(__builtin_amdgcn_ds_swizzle(__float_as_int(s), 0x401F));
  if (lane == 0) scA[w] = s;
  else if (lane == 32) scB[w] = s;
  __syncthreads();
  float e[16];
  float m = -3.0e38f;
#pragma unroll
  for (int p = 0; p < 16; ++p) {
    e[p] = (scA[p] + scB[p]) * 0.03125f;  // 1/sqrt(1024)
    m = fmaxf(m, e[p]);
  }
  float sum = 0.f;
#pragma unroll
  for (int p = 0; p < 16; ++p) {
    e[p] = expf(e[p] - m);
    sum += e[p];
  }
  const float inv = 1.f / sum;
  const float* arow = A + (size_t)n * (HH * 16) + (size_t)u * 16;
  float av = 0.f;
#pragma unroll
  for (int p = 0; p < 16; ++p) av = fmaf(arow[p], e[p], av);
  Aop[(size_t)n * KTOT + 2 * HH + u] = (bf16)(av * inv);
}

// One persistent kernel: convert weights, init state, then 64 x {GEMM phase,
// sync, cell phase, sync}. 256 wgs x 1024 threads (16 waves), 64 KB LDS.
__global__ __launch_bounds__(1024, 4) void fused_all(
    const float* __restrict__ x, const float* __restrict__ A,
    const float* __restrict__ Wx, const float* __restrict__ Wh,
    const float* __restrict__ Wattn, const float* __restrict__ bias,
    float* __restrict__ out, bf16* __restrict__ Wt, bf16* __restrict__ Aop,
    float* __restrict__ preact, float* __restrict__ c_ws,
    unsigned* __restrict__ bar_cnt, unsigned* __restrict__ bar_gen) {
  __shared__ __align__(16) bf16 lds[2][32 * 512];  // 64 KB (gemm dbuf)
  float* h_sh = (float*)&lds[0][0];                // cell-phase overlay
  float* scA = h_sh + 1024;
  float* scB = scA + 16;

  const int b = blockIdx.x, tid = threadIdx.x;
  const int lane = tid & 63, wid = tid >> 6;
  unsigned bar = 0;

  // ---- prologue A: convert weights (all wgs, 6 chunks/thread) ----
#pragma unroll
  for (int i = 0; i < 6; ++i) {
    const int g = i * (NWG * 1024) + b * 1024 + tid;
    const int tile = g >> 6, l = g & 63;
    const int ntile = tile / KTILES, ktile = tile % KTILES;
    const int n = ntile * 16 + (l & 15);
    const int k0 = ktile * 32 + (l >> 4) * 8;
    bf16x8 ov;
#pragma unroll
    for (int j = 0; j < 8; ++j) {
      const int k = k0 + j;
      float v;
      if (k < DD)            v = Wx[(size_t)k * NOUT + n];
      else if (k < DD + HH)  v = Wh[(size_t)(k - DD) * NOUT + n];
      else                   v = Wattn[(size_t)(k - DD - HH) * NOUT + n];
      ov[j] = (bf16)v;
    }
    *(bf16x8*)(Wt + (size_t)tile * 512 + l * 8) = ov;
  }

  // ---- prologue B: init h0/c0 + pack step-0 operand (wg b -> n=b) ----
  {
    const int n = b, u = tid;
    const float* arow = A + (size_t)n * (HH * 16) + (size_t)u * 16;
    float h0 = 0.f;
#pragma unroll
    for (int p = 0; p < 16; ++p) h0 += arow[p];
    h0 *= 0.0625f;
    c_ws[n * HH + u] = h0;
    h_sh[u] = h0;
    Aop[(size_t)n * KTOT + HH + u] = (bf16)h0;
    Aop[(size_t)n * KTOT + u] = (bf16)x[(size_t)n * TS * DD + u];
    __syncthreads();
    attn_tail(n, u, A, Aop, h_sh, scA, scB);
  }
  gsync(bar_cnt, bar_gen, ++bar);

  // ---- GEMM tile decode: 2 rt x 32 ct x 4 ks = 256 wgs; xcd <-> ct group
  // keeps each XCD's 3 MB weight slice L2-resident across all 64 steps.
  const int xcd = b & 7;
  const int ct = xcd * 4 + ((b >> 3) & 3);  // [0,32) tiles of 128 cols
  const int rt = (b >> 5) & 1;              // [0,2) tiles of 128 rows
  const int ks = b >> 6;                    // [0,4) K slices of 768
  const int wr = wid >> 2, wc = wid & 3;    // wave -> 32x32 out block

  // staging: wave wid stages A-tile wid and B-tile wid (each 64 lanes x 16B)
  const bf16* gA;
  const bf16* gB;
  const int ldsA = wid * 512, ldsB = (16 + wid) * 512;
  {
    const int mt = wid >> 1, kt = wid & 1;
    const int row = rt * 128 + mt * 16 + (lane & 15);
    gA = Aop + (size_t)row * KTOT + ks * 768 + kt * 32 + (lane >> 4) * 8;
    const int tileidx = (ct * 8 + mt) * KTILES + ks * KT_PER + kt;
    gB = Wt + (size_t)tileidx * 512 + lane * 8;
  }
  const int aoff00 = ((wr * 2 + 0) * 2 + 0) * 512 + lane * 8;
  const int aoff10 = ((wr * 2 + 1) * 2 + 0) * 512 + lane * 8;
  const int boff00 = 16 * 512 + ((wc * 2 + 0) * 2 + 0) * 512 + lane * 8;
  const int boff10 = 16 * 512 + ((wc * 2 + 1) * 2 + 0) * 512 + lane * 8;

  for (int t = 0; t < TS; ++t) {
    // ===== GEMM phase: preact[ks] = Aop(:, ks*768:+768) @ W-slice =====
    gload_lds16(gA, &lds[0][ldsA]);
    gload_lds16(gB, &lds[0][ldsB]);
    f32x4 acc[2][2];
#pragma unroll
    for (int i = 0; i < 2; ++i)
#pragma unroll
      for (int j = 0; j < 2; ++j) acc[i][j] = (f32x4){0.f, 0.f, 0.f, 0.f};

    for (int it = 0; it < GITERS; ++it) {
      __syncthreads();  // drains vmcnt: buf[it&1] staged, old readers done
      if (it < GITERS - 1) {
        gload_lds16(gA + (it + 1) * 64, &lds[(it + 1) & 1][ldsA]);
        gload_lds16(gB + (size_t)(it + 1) * 1024, &lds[(it + 1) & 1][ldsB]);
      }
      const bf16* buf = lds[it & 1];
#pragma unroll
      for (int kk = 0; kk < 2; ++kk) {
        const bf16x8 a0 = *(const bf16x8*)(buf + aoff00 + kk * 512);
        const bf16x8 a1 = *(const bf16x8*)(buf + aoff10 + kk * 512);
        const bf16x8 b0 = *(const bf16x8*)(buf + boff00 + kk * 512);
        const bf16x8 b1 = *(const bf16x8*)(buf + boff10 + kk * 512);
        acc[0][0] = __builtin_amdgcn_mfma_f32_16x16x32_bf16(a0, b0, acc[0][0], 0, 0, 0);
        acc[0][1] = __builtin_amdgcn_mfma_f32_16x16x32_bf16(a0, b1, acc[0][1], 0, 0, 0);
        acc[1][0] = __builtin_amdgcn_mfma_f32_16x16x32_bf16(a1, b0, acc[1][0], 0, 0, 0);
        acc[1][1] = __builtin_amdgcn_mfma_f32_16x16x32_bf16(a1, b1, acc[1][1], 0, 0, 0);
      }
    }
    {  // epilogue: C/D layout col=lane&15, row=(lane>>4)*4+r [m89-verified]
      float* pp = preact + (size_t)ks * PSTRIDE;
#pragma unroll
      for (int i = 0; i < 2; ++i) {
#pragma unroll
        for (int j = 0; j < 2; ++j) {
          const int row0 = rt * 128 + wr * 32 + i * 16 + (lane >> 4) * 4;
          const int col = ct * 128 + wc * 32 + j * 16 + (lane & 15);
#pragma unroll
          for (int r = 0; r < 4; ++r)
            pp[(size_t)(row0 + r) * NOUT + col] = acc[i][j][r];
        }
      }
    }
    gsync(bar_cnt, bar_gen, ++bar);

    // ===== cell phase (wg b -> n=b) =====
    {
      const int n = b, u = tid;
      const float* pr = preact + (size_t)n * NOUT;
#define PSUM(g) (pr[g * HH + u] + pr[PSTRIDE + g * HH + u] + \
                 pr[2 * PSTRIDE + g * HH + u] + pr[3 * PSTRIDE + g * HH + u] + bias[g * HH + u])
      const float ai = PSUM(0);
      const float af = PSUM(1);
      const float ao = PSUM(2);
      const float ag = PSUM(3);
#undef PSUM
      const float cold = c_ws[n * HH + u];
      const float si = 1.f / (1.f + expf(-ai));
      const float sf = 1.f / (1.f + expf(-af));
      const float so = 1.f / (1.f + expf(-ao));
      const float cn = sf * cold + si * tanhf(ag);
      const float hn = so * tanhf(cn);
      c_ws[n * HH + u] = cn;
      out[((size_t)n * TS + t) * HH + u] = hn;
      if (t < TS - 1) {  // uniform branch
        h_sh[u] = hn;
        Aop[(size_t)n * KTOT + HH + u] = (bf16)hn;
        Aop[(size_t)n * KTOT + u] = (bf16)x[((size_t)n * TS + t + 1) * DD + u];
        __syncthreads();
        attn_tail(n, u, A, Aop, h_sh, scA, scB);
      }
    }
    gsync(bar_cnt, bar_gen, ++bar);
  }
}

// ---------------------------------------------------------------------------
// ws layout (bytes):
//   [0, 25165824)            Wt      bf16 tiled weights (3072x4096)
//   [25165824, 26738688)     Aop     bf16 row-major operand (256x3072)
//   [26738688, 43515904)     preact  f32 x4 K-split partials (256x4096 each)
//   [43515904, 44564480)     c       f32 (256x1024)
//   [44564480, 44564488)     barrier cnt/gen (zeroed each call)
// ---------------------------------------------------------------------------
extern "C" void kernel_launch(void* const* d_in, const int* in_sizes, int n_in,
                              void* d_out, int out_size, void* d_ws, size_t ws_size,
                              hipStream_t stream) {
  const float* x     = (const float*)d_in[0];
  const float* A     = (const float*)d_in[1];
  const float* Wx    = (const float*)d_in[2];
  const float* Wh    = (const float*)d_in[3];
  const float* Wattn = (const float*)d_in[4];
  const float* bias  = (const float*)d_in[5];
  float* out = (float*)d_out;
  char* ws = (char*)d_ws;
  bf16* Wt        = (bf16*)(ws + 0);
  bf16* Aop       = (bf16*)(ws + 25165824);
  float* preact   = (float*)(ws + 26738688);
  float* c_ws     = (float*)(ws + 43515904);
  unsigned* barp  = (unsigned*)(ws + 44564480);

  hipMemsetAsync(barp, 0, 8, stream);  // barrier cnt=0, gen=0 (deterministic)
  fused_all<<<NWG, 1024, 0, stream>>>(x, A, Wx, Wh, Wattn, bias, out,
                                      Wt, Aop, preact, c_ws, barp, barp + 1);
}

// Round 6
// 2100.993 us; speedup vs baseline: 3.5172x; 3.5172x over previous
//
#include <hip/hip_runtime.h>

typedef __bf16 bf16;
typedef bf16 bf16x8 __attribute__((ext_vector_type(8)));
typedef float f32x4 __attribute__((ext_vector_type(4)));

#define NB 256     // batch
#define TS 64      // timesteps
#define DD 1024    // input dim
#define HH 1024    // hidden
#define KTOT 3072  // D + 2H (GEMM K)
#define NOUT 4096  // 4H
#define KTILES 96  // KTOT/32
#define GITERS 12  // per K-group: 768 / BK64

// Weight tiles are 16col x 32k fragments of 512 bf16 (1 KB); element (l,j):
// col = base + (l&15), k = kbase + (l>>4)*8 + j. Column order is PERMUTED
// gate-interleaved: tile tau covers original W column (tau&3)*1024 +
// (tau>>2)*16 + (l&15)  -> a wg owning 32 h x 4 gates reads 16 whole tiles
// per BK and can finish the LSTM cell locally (preact never hits memory).
// Activations Aop: plain row-major bf16 (256 x 3072), double-buffered by
// step parity; packed by the cell/attn epilogues with unit-stride stores.

static __device__ __forceinline__ void gload_lds16(const void* g, void* l) {
  __builtin_amdgcn_global_load_lds(
      (const __attribute__((address_space(1))) void*)g,
      (__attribute__((address_space(3))) void*)l, 16, 0, 0);
}

// Convert [Wx; Wh; Wattn] (3072 x 4096 f32 stacked on K) into gate-interleaved
// fragment-tiled bf16.
__global__ __launch_bounds__(256) void convert_w(const float* __restrict__ Wx,
                                                 const float* __restrict__ Wh,
                                                 const float* __restrict__ Wattn,
                                                 bf16* __restrict__ Wt) {
  const int gid = blockIdx.x * 256 + threadIdx.x;  // one 16B chunk per thread
  const int tile = gid >> 6;                       // tau*96 + kt, 0..24575
  const int l = gid & 63;
  const int tau = tile / KTILES;
  const int kt = tile % KTILES;
  const int col = (tau & 3) * 1024 + (tau >> 2) * 16 + (l & 15);
  const int k0 = kt * 32 + (l >> 4) * 8;
  bf16x8 ovec;
#pragma unroll
  for (int j = 0; j < 8; ++j) {
    const int k = k0 + j;
    float v;
    if (k < DD)            v = Wx[(size_t)k * NOUT + col];
    else if (k < DD + HH)  v = Wh[(size_t)(k - DD) * NOUT + col];
    else                   v = Wattn[(size_t)(k - DD - HH) * NOUT + col];
    ovec[j] = (bf16)v;
  }
  *(bf16x8*)(Wt + (size_t)tile * 512 + l * 8) = ovec;
}

// scores -> softmax -> attn -> pack (R3-proven). 1024 threads, h_sh written.
static __device__ __forceinline__ void attn_tail(
    int n, int u, const float* __restrict__ A, bf16* __restrict__ Aop,
    const float* __restrict__ h_sh, float* __restrict__ scA,
    float* __restrict__ scB) {
  const int lane = u & 63, w = u >> 6;
  const float* ap = A + (size_t)n * (HH * 16) + w;  // position p = w
  float s = 0.f;
#pragma unroll
  for (int i = 0; i < 16; ++i) {
    const int idx = lane + 64 * i;
    s = fmaf(h_sh[idx], ap[(size_t)idx * 16], s);
  }
  s += __int_as_float(__builtin_amdgcn_ds_swizzle(__float_as_int(s), 0x041F));
  s += __int_as_float(__builtin_amdgcn_ds_swizzle(__float_as_int(s), 0x081F));
  s += __int_as_float(__builtin_amdgcn_ds_swizzle(__float_as_int(s), 0x101F));
  s += __int_as_float(__builtin_amdgcn_ds_swizzle(__float_as_int(s), 0x201F));
  s += __int_as_float(__builtin_amdgcn_ds_swizzle(__float_as_int(s), 0x401F));
  if (lane == 0) scA[w] = s;
  else if (lane == 32) scB[w] = s;
  __syncthreads();
  float e[16];
  float m = -3.0e38f;
#pragma unroll
  for (int p = 0; p < 16; ++p) {
    e[p] = (scA[p] + scB[p]) * 0.03125f;  // 1/sqrt(1024)
    m = fmaxf(m, e[p]);
  }
  float sum = 0.f;
#pragma unroll
  for (int p = 0; p < 16; ++p) {
    e[p] = expf(e[p] - m);
    sum += e[p];
  }
  const float inv = 1.f / sum;
  const float* arow = A + (size_t)n * (HH * 16) + (size_t)u * 16;
  float av = 0.f;
#pragma unroll
  for (int p = 0; p < 16; ++p) av = fmaf(arow[p], e[p], av);
  Aop[(size_t)n * KTOT + 2 * HH + u] = (bf16)(av * inv);
}

// h0 = mean(A); c0 = h0; pack [x0 | h0 | attn0] into Aop buffer 0.
__global__ __launch_bounds__(1024) void init_kernel(const float* __restrict__ A,
                                                    const float* __restrict__ x,
                                                    float* __restrict__ c_ws,
                                                    bf16* __restrict__ Aop) {
  __shared__ float h_sh[HH];
  __shared__ float scA[16], scB[16];
  const int n = (blockIdx.x & 7) * 32 + (blockIdx.x >> 3);
  const int u = threadIdx.x;
  const float* arow = A + (size_t)n * (HH * 16) + (size_t)u * 16;
  float h0 = 0.f;
#pragma unroll
  for (int p = 0; p < 16; ++p) h0 += arow[p];
  h0 *= 0.0625f;
  c_ws[n * HH + u] = h0;
  h_sh[u] = h0;
  Aop[(size_t)n * KTOT + HH + u] = (bf16)h0;
  Aop[(size_t)n * KTOT + u] = (bf16)x[(size_t)n * TS * DD + u];
  __syncthreads();
  attn_tail(n, u, A, Aop, h_sh, scA, scB);
}

// attn for step t+1: reads h_ws (written by gemm_cell), writes Aop_nxt attn
// cols. XCD-pinned n-slices keep each XCD's 2.1 MB A slice L2-warm.
__global__ __launch_bounds__(1024) void attn_kernel(const float* __restrict__ h_ws,
                                                    const float* __restrict__ A,
                                                    bf16* __restrict__ Aop_nxt) {
  __shared__ float h_sh[HH];
  __shared__ float scA[16], scB[16];
  const int n = (blockIdx.x & 7) * 32 + (blockIdx.x >> 3);
  const int u = threadIdx.x;
  h_sh[u] = h_ws[n * HH + u];
  __syncthreads();
  attn_tail(n, u, A, Aop_nxt, h_sh, scA, scB);
}

// ---------------------------------------------------------------------------
// Fused GEMM + LSTM cell. wg (rt, ht): 32 n-rows x (32 h x 4 gates) output.
// 16 waves = 4 K-groups (K=768 each) x 4 gate-waves; wave tile 32x32.
// A: global_load_lds staged (4x reuse); B: direct global->reg (no reuse).
// K-group partials reduced via LDS (two 16-h phases); cell finishes locally.
// ---------------------------------------------------------------------------
#define SMEM_BYTES 36864  // max(A-staging 32768, red 4*4*16*36*4 = 36864)

__global__ __launch_bounds__(1024, 4) void gemm_cell(
    const bf16* __restrict__ Aop_cur, bf16* __restrict__ Aop_nxt,
    const bf16* __restrict__ Wt, const float* __restrict__ bias,
    const float* __restrict__ x, float* __restrict__ c_ws,
    float* __restrict__ h_ws, float* __restrict__ out, const int t) {
  __shared__ __align__(16) char smem[SMEM_BYTES];
  bf16* astg = (bf16*)smem;   // [kg][buf][tl][512] bf16 = 32 KB
  float* red = (float*)smem;  // [kg][g][16][36] f32 = 36864 B (union, after loop)

  const int b = blockIdx.x;
  const int xcd = b & 7;
  const int ht = xcd * 4 + ((b >> 3) & 3);  // [0,32): h-range [ht*32, +32)
  const int rt = b >> 5;                    // [0,8):  n-range [rt*32, +32)
  const int tid = threadIdx.x, lane = tid & 63, wid = tid >> 6;
  const int kg = wid >> 2;  // K-group: K in [kg*768, +768)
  const int g = wid & 3;    // gate wave (also stages A tile tl=g)

  // A staging: wave stages tile tl=g of its group: (mt=g&1, kk=g>>1)
  const bf16* gA = Aop_cur +
      (size_t)(rt * 32 + (g & 1) * 16 + (lane & 15)) * KTOT +
      kg * 768 + (g >> 1) * 32 + (lane >> 4) * 8;
  const int stg_base = (kg * 2) * 4 * 512 + g * 512;  // + buf*2048

  // B frag pointers (nt, kk), advance 1024 elems (2 k-tiles) per iter
  const bf16* gB0 = Wt + ((size_t)((ht * 2 + 0) * 4 + g) * KTILES + kg * 24 + 0) * 512 + lane * 8;
  const bf16* gB1 = Wt + ((size_t)((ht * 2 + 0) * 4 + g) * KTILES + kg * 24 + 1) * 512 + lane * 8;
  const bf16* gB2 = Wt + ((size_t)((ht * 2 + 1) * 4 + g) * KTILES + kg * 24 + 0) * 512 + lane * 8;
  const bf16* gB3 = Wt + ((size_t)((ht * 2 + 1) * 4 + g) * KTILES + kg * 24 + 1) * 512 + lane * 8;

  // prologue: stage A buf0, load B it=0
  gload_lds16(gA, astg + stg_base);
  bf16x8 bc0 = *(const bf16x8*)gB0;
  bf16x8 bc1 = *(const bf16x8*)gB1;
  bf16x8 bc2 = *(const bf16x8*)gB2;
  bf16x8 bc3 = *(const bf16x8*)gB3;

  f32x4 acc00 = {0,0,0,0}, acc01 = {0,0,0,0}, acc10 = {0,0,0,0}, acc11 = {0,0,0,0};

  for (int it = 0; it < GITERS; ++it) {
    __syncthreads();  // A buf(it&1) staged (vmcnt drained); prev readers done
    bf16x8 bn0, bn1, bn2, bn3;
    if (it < GITERS - 1) {
      gload_lds16(gA + (it + 1) * 64, astg + stg_base + ((it + 1) & 1) * 2048);
      bn0 = *(const bf16x8*)(gB0 + (it + 1) * 1024);
      bn1 = *(const bf16x8*)(gB1 + (it + 1) * 1024);
      bn2 = *(const bf16x8*)(gB2 + (it + 1) * 1024);
      bn3 = *(const bf16x8*)(gB3 + (it + 1) * 1024);
    }
    const bf16* abuf = astg + (kg * 2 + (it & 1)) * 4 * 512;
    const bf16x8 a00 = *(const bf16x8*)(abuf + 0 * 512 + lane * 8);  // mr0 kk0
    const bf16x8 a10 = *(const bf16x8*)(abuf + 1 * 512 + lane * 8);  // mr1 kk0
    const bf16x8 a01 = *(const bf16x8*)(abuf + 2 * 512 + lane * 8);  // mr0 kk1
    const bf16x8 a11 = *(const bf16x8*)(abuf + 3 * 512 + lane * 8);  // mr1 kk1
    acc00 = __builtin_amdgcn_mfma_f32_16x16x32_bf16(a00, bc0, acc00, 0, 0, 0);
    acc01 = __builtin_amdgcn_mfma_f32_16x16x32_bf16(a00, bc2, acc01, 0, 0, 0);
    acc10 = __builtin_amdgcn_mfma_f32_16x16x32_bf16(a10, bc0, acc10, 0, 0, 0);
    acc11 = __builtin_amdgcn_mfma_f32_16x16x32_bf16(a10, bc2, acc11, 0, 0, 0);
    acc00 = __builtin_amdgcn_mfma_f32_16x16x32_bf16(a01, bc1, acc00, 0, 0, 0);
    acc01 = __builtin_amdgcn_mfma_f32_16x16x32_bf16(a01, bc3, acc01, 0, 0, 0);
    acc10 = __builtin_amdgcn_mfma_f32_16x16x32_bf16(a11, bc1, acc10, 0, 0, 0);
    acc11 = __builtin_amdgcn_mfma_f32_16x16x32_bf16(a11, bc3, acc11, 0, 0, 0);
    if (it < GITERS - 1) { bc0 = bn0; bc1 = bn1; bc2 = bn2; bc3 = bn3; }
  }

  __syncthreads();  // all A ds_reads consumed: astg dead, red region live

  // two phases: p=0 -> frag nt=0 (hl 0..15), p=1 -> frag nt=1 (hl 16..31)
#pragma unroll
  for (int p = 0; p < 2; ++p) {
    if (p) __syncthreads();  // phase-0 reads done before phase-1 writes
    {  // write acc frags nt=p: C/D layout col=lane&15, row=(lane>>4)*4+r
      const int s = ((kg * 4 + g) * 16 + (lane & 15)) * 36 + (lane >> 4) * 4;
      *(f32x4*)&red[s] = p ? acc01 : acc00;           // mr=0
      *(f32x4*)&red[s + 16] = p ? acc11 : acc10;      // mr=1
    }
    __syncthreads();
    if (tid < 512) {  // wave-uniform: waves 0-7
      const int nloc = tid >> 4, hl16 = tid & 15;
      const int n = rt * 32 + nloc;
      const int h = ht * 32 + p * 16 + hl16;
      float gate[4];
#pragma unroll
      for (int gg = 0; gg < 4; ++gg) {
        float v = bias[gg * HH + h];
#pragma unroll
        for (int kk = 0; kk < 4; ++kk)
          v += red[((kk * 4 + gg) * 16 + hl16) * 36 + nloc];
        gate[gg] = v;
      }
      const float cold = c_ws[n * HH + h];
      const float si = 1.f / (1.f + expf(-gate[0]));
      const float sf = 1.f / (1.f + expf(-gate[1]));
      const float so = 1.f / (1.f + expf(-gate[2]));
      const float cn = sf * cold + si * tanhf(gate[3]);
      const float hn = so * tanhf(cn);
      c_ws[n * HH + h] = cn;
      out[((size_t)n * TS + t) * HH + h] = hn;
      h_ws[n * HH + h] = hn;
      if (t < TS - 1) {  // pack next step's x and h columns
        Aop_nxt[(size_t)n * KTOT + HH + h] = (bf16)hn;
        Aop_nxt[(size_t)n * KTOT + h] = (bf16)x[((size_t)n * TS + t + 1) * DD + h];
      }
    }
  }
}

// ---------------------------------------------------------------------------
// ws layout (bytes):
//   [0, 25165824)            Wt    bf16 tiled weights (perm cols, 3072x4096)
//   [25165824, 26738688)     Aop0  bf16 row-major (256x3072)
//   [26738688, 28311552)     Aop1  bf16 row-major (256x3072)
//   [28311552, 29360128)     c_ws  f32 (256x1024)
//   [29360128, 30408704)     h_ws  f32 (256x1024)
// total ~30.4 MB
// ---------------------------------------------------------------------------
extern "C" void kernel_launch(void* const* d_in, const int* in_sizes, int n_in,
                              void* d_out, int out_size, void* d_ws, size_t ws_size,
                              hipStream_t stream) {
  const float* x     = (const float*)d_in[0];
  const float* A     = (const float*)d_in[1];
  const float* Wx    = (const float*)d_in[2];
  const float* Wh    = (const float*)d_in[3];
  const float* Wattn = (const float*)d_in[4];
  const float* bias  = (const float*)d_in[5];
  float* out = (float*)d_out;
  char* ws = (char*)d_ws;
  bf16* Wt     = (bf16*)(ws + 0);
  bf16* Aop[2] = {(bf16*)(ws + 25165824), (bf16*)(ws + 26738688)};
  float* c_ws  = (float*)(ws + 28311552);
  float* h_ws  = (float*)(ws + 29360128);

  convert_w<<<6144, 256, 0, stream>>>(Wx, Wh, Wattn, Wt);
  init_kernel<<<NB, 1024, 0, stream>>>(A, x, c_ws, Aop[0]);
  for (int t = 0; t < TS; ++t) {
    gemm_cell<<<NB, 1024, 0, stream>>>(Aop[t & 1], Aop[(t + 1) & 1], Wt, bias,
                                       x, c_ws, h_ws, out, t);
    if (t < TS - 1)
      attn_kernel<<<NB, 1024, 0, stream>>>(h_ws, A, Aop[(t + 1) & 1]);
  }
}